// Round 9
// baseline (160.676 us; speedup 1.0000x reference)
//
#include <hip/hip_runtime.h>
#include <math.h>

#define Bn 8
#define Hn 128
#define Pn 128
#define Ln 4096
#define LF 2049           // Ln/2 + 1
#define NROWS (Bn*Hn)     // 1024
#define NT 32             // frequency columns per mixmm block
#define NTILES 65         // ceil(2049/32) per batch
#define PLSZ 4096         // halfs per data plane (32 x 128)
#define WPLSZ 16384       // halfs per weight plane (128 x 128)
#define TSCALE 64.0f      // T stored as T/64 (fp16 range guard); W2 pre-scaled x64

// LDS skew for FFT buffers: +1 float2 every 16 -> strided Stockham writes <=2-way
#define SKEW(a) ((a) + ((a) >> 4))
#define FBUF 2176          // SKEW(2047)+1 rounded up

typedef _Float16 f16x8 __attribute__((ext_vector_type(8)));
typedef float f32x4 __attribute__((ext_vector_type(4)));

// native sin/cos (v_sin_f32 path) — fine for fp16-bound weight prep
__device__ __forceinline__ void fsincos(float a, float* s, float* c) {
    *s = __sinf(a);
    *c = __cosf(a);
}

// ---------------------------------------------------------------------------
// prep (ONE kernel): fold H-axis FFTs into fp16 weight planes {r, i} AND
// build the FFT twiddle table tw[m] = e^{-2*pi*i*m/2048} (accurate OCML
// sincos — exact-to-fp32 twiddles, shared by every FFT block, L2-hot).
//   blocks   0- 63: W1[p][h] = (B_bar @ F)[p][h]
//   blocks  64-127: W2[h][p] = (Finv @ C)[h][p] * TSCALE
//   blocks 128-143: W3[h][q] = (Finv @ (D @ F))[h][q]  (two-phase via LDS)
//   blocks 144-151: tw table (256 entries each)
// ---------------------------------------------------------------------------
__device__ __forceinline__ void write2(_Float16* __restrict__ W, int idx,
                                       float vr, float vi) {
    W[0 * WPLSZ + idx] = (_Float16)vr;
    W[1 * WPLSZ + idx] = (_Float16)vi;
}

__global__ __launch_bounds__(256) void prep_all_k(
        const float* __restrict__ B_ri, const float* __restrict__ C_ri,
        const float* __restrict__ D_ri,
        _Float16* __restrict__ W1, _Float16* __restrict__ W2,
        _Float16* __restrict__ W3, float2* __restrict__ tw) {
    const int bid = blockIdx.x;
    const int tid = threadIdx.x;
    if (bid < 64) {
        int idx = bid * 256 + tid;          // p*128 + h
        int rrow = idx >> 7, ccol = idx & 127;
        float sr = 0.f, si = 0.f;
        for (int q = 0; q < 128; ++q) {
            float br = B_ri[(rrow * 128 + q) * 2 + 0];
            float bi = B_ri[(rrow * 128 + q) * 2 + 1];
            float ang = -3.14159265358979f * (float)((q * ccol) & 127) / 64.0f;
            float sw, cw; fsincos(ang, &sw, &cw);
            sr += br * cw - bi * sw;
            si += br * sw + bi * cw;
        }
        write2(W1, idx, sr, si);
    } else if (bid < 128) {
        int idx = (bid - 64) * 256 + tid;   // h*128 + p
        int rrow = idx >> 7, ccol = idx & 127;
        float sr = 0.f, si = 0.f;
        for (int h2 = 0; h2 < 128; ++h2) {
            float cr = C_ri[(h2 * 128 + ccol) * 2 + 0];
            float ci = C_ri[(h2 * 128 + ccol) * 2 + 1];
            float ang = 3.14159265358979f * (float)((rrow * h2) & 127) / 64.0f;
            float sw, cw; fsincos(ang, &sw, &cw);
            sr += cr * cw - ci * sw;
            si += cr * sw + ci * cw;
        }
        write2(W2, idx, sr * (TSCALE / 128.0f), si * (TSCALE / 128.0f));
    } else if (bid < 144) {
        // W3 two-phase: G = Finv @ D (8 rows in LDS), then W3 = G @ F
        __shared__ float2 Gs[8][128];
        const int h0 = (bid - 128) * 8;
        const int hh = tid >> 5;            // 0..7
        const int c0 = (tid & 31) * 4;
        float2 g[4];
        #pragma unroll
        for (int cc = 0; cc < 4; ++cc) g[cc] = make_float2(0.f, 0.f);
        for (int a = 0; a < 128; ++a) {
            float ang = 3.14159265358979f * (float)(((h0 + hh) * a) & 127) / 64.0f;
            float sw, cw; fsincos(ang, &sw, &cw);
            #pragma unroll
            for (int cc = 0; cc < 4; ++cc) {
                float dr = D_ri[(a * 128 + c0 + cc) * 2 + 0];
                float di = D_ri[(a * 128 + c0 + cc) * 2 + 1];
                g[cc].x += dr * cw - di * sw;
                g[cc].y += dr * sw + di * cw;
            }
        }
        #pragma unroll
        for (int cc = 0; cc < 4; ++cc)
            Gs[hh][c0 + cc] = make_float2(g[cc].x * (1.0f / 128.0f),
                                          g[cc].y * (1.0f / 128.0f));
        __syncthreads();
        float2 wacc[4];
        #pragma unroll
        for (int qq = 0; qq < 4; ++qq) wacc[qq] = make_float2(0.f, 0.f);
        for (int c = 0; c < 128; ++c) {
            float2 gv = Gs[hh][c];
            #pragma unroll
            for (int qq = 0; qq < 4; ++qq) {
                float ang = -3.14159265358979f * (float)((c * (c0 + qq)) & 127) / 64.0f;
                float sw, cw; fsincos(ang, &sw, &cw);
                wacc[qq].x += gv.x * cw - gv.y * sw;
                wacc[qq].y += gv.x * sw + gv.y * cw;
            }
        }
        #pragma unroll
        for (int qq = 0; qq < 4; ++qq)
            write2(W3, (h0 + hh) * 128 + c0 + qq, wacc[qq].x, wacc[qq].y);
    } else {
        // twiddle table, accurate sincos
        int m = (bid - 144) * 256 + tid;    // 0..2047
        float ang = -3.14159265358979f * (float)m / 1024.0f;   // -2*pi*m/2048
        float sw, cw;
        __sincosf(ang, &sw, &cw);
        tw[m] = make_float2(cw, sw);
    }
}

// ---------------------------------------------------------------------------
// 2048-pt Stockham FFT in LDS: radix-8 x3 + radix-4 (final, twiddle-free).
// Twiddles from the global table: stage-s twiddle W_n^{pj} = tw[j*(k-q)]
// (since p*2048/n == k-q). 7 independent 8-B L2-hot loads replace 14
// quarter-rate transcendentals + their dependency chain (the per-butterfly
// serial-path theory; sincos-flavor swaps r7/r8 were neutral).
// ---------------------------------------------------------------------------
__device__ __forceinline__ float2 cadd2(float2 a, float2 b) { return make_float2(a.x + b.x, a.y + b.y); }
__device__ __forceinline__ float2 csub2(float2 a, float2 b) { return make_float2(a.x - b.x, a.y - b.y); }

template <int SIGN>
__device__ __forceinline__ void dft4(float2 a0, float2 a1, float2 a2, float2 a3,
                                     float2& y0, float2& y1, float2& y2, float2& y3) {
    float t0x = a0.x + a2.x, t0y = a0.y + a2.y;
    float t1x = a0.x - a2.x, t1y = a0.y - a2.y;
    float t2x = a1.x + a3.x, t2y = a1.y + a3.y;
    float t3x = a1.x - a3.x, t3y = a1.y - a3.y;
    y0 = make_float2(t0x + t2x, t0y + t2y);
    y2 = make_float2(t0x - t2x, t0y - t2y);
    y1 = make_float2(t1x - (float)SIGN * t3y, t1y + (float)SIGN * t3x);
    y3 = make_float2(t1x + (float)SIGN * t3y, t1y - (float)SIGN * t3x);
}

template <int SIGN>
__device__ __forceinline__ void fft2048(float2* bufA, float2* bufB,
                                        const float2* __restrict__ tw) {
    const int tid = threadIdx.x;
    float2* src = bufA;
    float2* dst = bufB;
    #pragma unroll
    for (int stg = 0; stg < 3; ++stg) {
        const int ls = 3 * stg;           // s = 8^stg
        const int k = tid;                // 256 butterflies
        const int q = k & ((1 << ls) - 1);
        const int mbase = k - q;          // p << ls  ==  p*2048/n
        float2 a[8];
        #pragma unroll
        for (int u = 0; u < 8; ++u) a[u] = src[SKEW(k + (u << 8))];
        // batch the 7 twiddle loads up front (independent, one waitcnt)
        float2 t1 = tw[mbase],     t2 = tw[2 * mbase], t3 = tw[3 * mbase];
        float2 t4 = tw[4 * mbase], t5 = tw[5 * mbase], t6 = tw[6 * mbase];
        float2 t7 = tw[7 * mbase];
        float2 A0, A1, A2, A3, B0, B1, B2, B3;
        dft4<SIGN>(a[0], a[2], a[4], a[6], A0, A1, A2, A3);
        dft4<SIGN>(a[1], a[3], a[5], a[7], B0, B1, B2, B3);
        const float c45 = 0.70710678118655f;
        float2 w1 = make_float2(c45 * (B1.x - (float)SIGN * B1.y), c45 * ((float)SIGN * B1.x + B1.y));
        float2 w2 = make_float2(-(float)SIGN * B2.y, (float)SIGN * B2.x);
        float2 w3 = make_float2(c45 * (-B3.x - (float)SIGN * B3.y), c45 * ((float)SIGN * B3.x - B3.y));
        float2 b[8];
        b[0] = cadd2(A0, B0);  b[4] = csub2(A0, B0);
        b[1] = cadd2(A1, w1);  b[5] = csub2(A1, w1);
        b[2] = cadd2(A2, w2);  b[6] = csub2(A2, w2);
        b[3] = cadd2(A3, w3);  b[7] = csub2(A3, w3);
        float2 twj[8];
        twj[1] = t1; twj[2] = t2; twj[3] = t3; twj[4] = t4;
        twj[5] = t5; twj[6] = t6; twj[7] = t7;
        #pragma unroll
        for (int j = 1; j < 8; ++j) {
            float cj = twj[j].x;
            float sj = (float)SIGN * twj[j].y;   // table is e^{-i...}; SIGN=+1 conjugates
            b[j] = make_float2(b[j].x * cj + b[j].y * sj, -b[j].x * sj + b[j].y * cj);
        }
        const int base = q + (mbase << 3);
        #pragma unroll
        for (int j = 0; j < 8; ++j) dst[SKEW(base + (j << ls))] = b[j];
        __syncthreads();
        float2* t = src; src = dst; dst = t;
    }
    // final radix-4: s=512, m=1 -> p=0, twiddles = 1
    #pragma unroll
    for (int r = 0; r < 2; ++r) {
        int k = tid + (r << 8);
        float2 a0 = src[SKEW(k)];
        float2 a1 = src[SKEW(k + 512)];
        float2 a2 = src[SKEW(k + 1024)];
        float2 a3 = src[SKEW(k + 1536)];
        float2 y0, y1, y2, y3;
        dft4<SIGN>(a0, a1, a2, a3, y0, y1, y2, y3);
        dst[SKEW(k)] = y0;
        dst[SKEW(k + 512)] = y1;
        dst[SKEW(k + 1024)] = y2;
        dst[SKEW(k + 1536)] = y3;
    }
    __syncthreads();
    // stages: A->B, B->A, A->B, B->A  => result in bufA
}

// Twiddle sign check: forward (SIGN=-1) needs e^{-2pi i j p/n} = (c, s) from
// the table -> b*(c + i s): re = bx*c - by*s; with sj = -s (SIGN=-1):
// re = bx*c + by*sj ✓ matches the rotated form above.

// rfft via real-packing: z[n] = u[2n] + i u[2n+1]; U from Z by even/odd unpack.
__global__ __launch_bounds__(256, 4) void rfft_rows_k(const float* __restrict__ u,
                                                      float2* __restrict__ Uhat,
                                                      const float2* __restrict__ tw) {
    __shared__ __align__(16) float2 bufA[FBUF];
    __shared__ __align__(16) float2 bufB[FBUF];
    const int row = blockIdx.x;
    const int tid = threadIdx.x;
    const float4* up4 = (const float4*)(u + (size_t)row * Ln);
    #pragma unroll
    for (int r = 0; r < 4; ++r) {
        float4 v = up4[tid + (r << 8)];
        int i = 2 * (tid + (r << 8));
        bufA[SKEW(i)] = make_float2(v.x, v.y);
        bufA[SKEW(i + 1)] = make_float2(v.z, v.w);
    }
    __syncthreads();
    fft2048<-1>(bufA, bufB, tw);
    float2* op = Uhat + (size_t)row * LF;
    for (int l = tid; l < 1025; l += 256) {
        float2 Zl = bufA[SKEW(l)];
        float2 Zm = bufA[SKEW((2048 - l) & 2047)];
        float2 Fe = make_float2(0.5f * (Zl.x + Zm.x), 0.5f * (Zl.y - Zm.y));
        float2 Dv = make_float2(0.5f * (Zl.x - Zm.x), 0.5f * (Zl.y + Zm.y));
        float2 Fo = make_float2(Dv.y, -Dv.x);                 // Dv / i
        float s, c; fsincos(-3.14159265358979f * (float)l / 2048.0f, &s, &c);
        float2 TF = make_float2(Fo.x * c - Fo.y * s, Fo.x * s + Fo.y * c);
        op[l] = make_float2(Fe.x + TF.x, Fe.y + TF.y);
        op[2048 - l] = make_float2(Fe.x - TF.x, -(Fe.y - TF.y));   // conj(Fe - TF)
    }
}

// irfft via inverse packing: Z[l] = Fe + i Fo rebuilt from U, then 2048 IFFT,
// y[2n]=Re(z), y[2n+1]=Im(z), scale 1/2048, exact GELU. float4 stores.
__global__ __launch_bounds__(256, 4) void irfft_gelu_k(const float2* __restrict__ Uhat,
                                                       float* __restrict__ out,
                                                       const float2* __restrict__ tw) {
    __shared__ __align__(16) float2 bufA[FBUF];
    __shared__ __align__(16) float2 bufB[FBUF];
    const int row = blockIdx.x;
    const int tid = threadIdx.x;
    const float2* wp = Uhat + (size_t)row * LF;
    for (int l = tid; l < 1025; l += 256) {
        float2 Ul = wp[l];
        float2 Um = wp[2048 - l];
        float2 Fe = make_float2(0.5f * (Ul.x + Um.x), 0.5f * (Ul.y - Um.y));
        float2 Dv = make_float2(0.5f * (Ul.x - Um.x), 0.5f * (Ul.y + Um.y));
        float s, c; fsincos(3.14159265358979f * (float)l / 2048.0f, &s, &c);
        float2 Fo = make_float2(Dv.x * c - Dv.y * s, Dv.x * s + Dv.y * c);
        bufA[SKEW(l)] = make_float2(Fe.x - Fo.y, Fe.y + Fo.x);          // Fe + i Fo
        if (l >= 1 && l <= 1023)
            bufA[SKEW(2048 - l)] = make_float2(Fe.x + Fo.y, Fo.x - Fe.y); // conj(Fe)+i conj(Fo)
    }
    __syncthreads();
    fft2048<1>(bufA, bufB, tw);
    float4* op4 = (float4*)(out + (size_t)row * Ln);
    #pragma unroll
    for (int r = 0; r < 4; ++r) {
        int n = 2 * (tid + (r << 8));
        float2 z0 = bufA[SKEW(n)];
        float2 z1 = bufA[SKEW(n + 1)];
        float y0 = z0.x * (1.0f / 2048.0f);
        float y1 = z0.y * (1.0f / 2048.0f);
        float y2 = z1.x * (1.0f / 2048.0f);
        float y3 = z1.y * (1.0f / 2048.0f);
        op4[tid + (r << 8)] = make_float4(
            0.5f * y0 * (1.0f + erff(y0 * 0.70710678118655f)),
            0.5f * y1 * (1.0f + erff(y1 * 0.70710678118655f)),
            0.5f * y2 * (1.0f + erff(y2 * 0.70710678118655f)),
            0.5f * y3 * (1.0f + erff(y3 * 0.70710678118655f)));
    }
}

// ---------------------------------------------------------------------------
// mixmm: NT=32 columns/block (byte-identical to r7/r8 — 59 -> ~30 us).
// ---------------------------------------------------------------------------
__device__ __forceinline__ f32x4 mfma16h(f16x8 a, f16x8 b, f32x4 c) {
    return __builtin_amdgcn_mfma_f32_16x16x32_f16(a, b, c, 0, 0, 0);
}
__device__ __forceinline__ f16x8 read_frag(const _Float16* plane, int n, int k) {
    int ksw = k ^ ((n & 7) << 3);
    return *(const f16x8*)(plane + n * 128 + ksw);
}
__device__ __forceinline__ f16x8 aread(const _Float16* W, int pl, int m, int k) {
    return *(const f16x8*)(W + pl * WPLSZ + m * 128 + k);
}

__global__ __launch_bounds__(256, 4) void mixmm_k(float2* __restrict__ Uhat,
                                                  const _Float16* __restrict__ W1,
                                                  const _Float16* __restrict__ W2,
                                                  const _Float16* __restrict__ W3,
                                                  const float* __restrict__ Lam) {
    __shared__ __align__(16) _Float16 Up[2 * PLSZ];      // 16 KB  {r, i}
    __shared__ __align__(16) _Float16 Tp[2 * PLSZ];      // 16 KB  {r, i}

    const int tid = threadIdx.x;
    const int b = blockIdx.x / NTILES;
    const int tile = blockIdx.x % NTILES;
    const int l0 = tile * NT;
    const int ncols = (LF - l0) < NT ? (LF - l0) : NT;

    {
        int n = tid & 31, kc = tid >> 5;
        float2 v[16];
        #pragma unroll
        for (int j = 0; j < 16; ++j) {
            int h = kc * 16 + j;
            v[j] = (n < ncols) ? Uhat[(size_t)(b * 128 + h) * LF + l0 + n]
                               : make_float2(0.f, 0.f);
        }
        #pragma unroll
        for (int jc = 0; jc < 2; ++jc) {
            f16x8 fr, fi;
            #pragma unroll
            for (int j = 0; j < 8; ++j) {
                fr[j] = (_Float16)v[jc * 8 + j].x;
                fi[j] = (_Float16)v[jc * 8 + j].y;
            }
            int ksw = (kc * 16 + jc * 8) ^ ((n & 7) << 3);
            *(f16x8*)(Up + 0 * PLSZ + n * 128 + ksw) = fr;
            *(f16x8*)(Up + 1 * PLSZ + n * 128 + ksw) = fi;
        }
    }
    __syncthreads();

    const int lane = tid & 63;
    const int w = tid >> 6;
    const int m15 = lane & 15;
    const int quad = lane >> 4;

    f32x4 accR[2][2], accM[2][2], accI[2][2];
    #pragma unroll
    for (int s = 0; s < 2; ++s)
        #pragma unroll
        for (int t = 0; t < 2; ++t) {
            accR[s][t] = (f32x4)0.f; accM[s][t] = (f32x4)0.f; accI[s][t] = (f32x4)0.f;
        }

    #pragma unroll
    for (int kb = 0; kb < 4; ++kb) {
        int k = kb * 32 + quad * 8;
        f16x8 wr[2], wi[2];
        #pragma unroll
        for (int s = 0; s < 2; ++s) {
            int m = w * 32 + s * 16 + m15;
            wr[s] = aread(W1, 0, m, k);
            wi[s] = aread(W1, 1, m, k);
        }
        f16x8 br[2], bi[2];
        #pragma unroll
        for (int t = 0; t < 2; ++t) {
            br[t] = read_frag(Up + 0 * PLSZ, t * 16 + m15, k);
            bi[t] = read_frag(Up + 1 * PLSZ, t * 16 + m15, k);
        }
        #pragma unroll
        for (int s = 0; s < 2; ++s)
            #pragma unroll
            for (int t = 0; t < 2; ++t) {
                accR[s][t] = mfma16h(wr[s], br[t], accR[s][t]);
                accM[s][t] = mfma16h(wi[s], bi[t], accM[s][t]);
                accI[s][t] = mfma16h(wr[s], bi[t], accI[s][t]);
                accI[s][t] = mfma16h(wi[s], br[t], accI[s][t]);
            }
    }

    #pragma unroll
    for (int s = 0; s < 2; ++s) {
        #pragma unroll
        for (int reg = 0; reg < 4; ++reg) {
            int p = w * 32 + s * 16 + quad * 4 + reg;
            float2 lamv = ((const float2*)Lam)[p];
            float dr = -lamv.x;
            #pragma unroll
            for (int t = 0; t < 2; ++t) {
                int n = t * 16 + m15;
                int l = l0 + n;
                float di = 3.14159265358979f * (float)l / 2048.0f - lamv.y;
                float inv = (1.0f / TSCALE) / (dr * dr + di * di);
                float xr = accR[s][t][reg] - accM[s][t][reg];
                float xi = accI[s][t][reg];
                float tr = (xr * dr + xi * di) * inv;
                float ti = (xi * dr - xr * di) * inv;
                int off = n * 128 + (p ^ ((n & 7) << 3));
                Tp[0 * PLSZ + off] = (_Float16)tr;
                Tp[1 * PLSZ + off] = (_Float16)ti;
            }
        }
    }
    __syncthreads();

    #pragma unroll
    for (int s = 0; s < 2; ++s)
        #pragma unroll
        for (int t = 0; t < 2; ++t) {
            accR[s][t] = (f32x4)0.f; accM[s][t] = (f32x4)0.f; accI[s][t] = (f32x4)0.f;
        }

    #pragma unroll
    for (int kb = 0; kb < 4; ++kb) {
        int k = kb * 32 + quad * 8;
        {
            f16x8 wr[2], wi[2];
            #pragma unroll
            for (int s = 0; s < 2; ++s) {
                int m = w * 32 + s * 16 + m15;
                wr[s] = aread(W2, 0, m, k);
                wi[s] = aread(W2, 1, m, k);
            }
            f16x8 br[2], bi[2];
            #pragma unroll
            for (int t = 0; t < 2; ++t) {
                br[t] = read_frag(Tp + 0 * PLSZ, t * 16 + m15, k);
                bi[t] = read_frag(Tp + 1 * PLSZ, t * 16 + m15, k);
            }
            #pragma unroll
            for (int s = 0; s < 2; ++s)
                #pragma unroll
                for (int t = 0; t < 2; ++t) {
                    accR[s][t] = mfma16h(wr[s], br[t], accR[s][t]);
                    accM[s][t] = mfma16h(wi[s], bi[t], accM[s][t]);
                    accI[s][t] = mfma16h(wr[s], bi[t], accI[s][t]);
                    accI[s][t] = mfma16h(wi[s], br[t], accI[s][t]);
                }
        }
        {
            f16x8 wr[2], wi[2];
            #pragma unroll
            for (int s = 0; s < 2; ++s) {
                int m = w * 32 + s * 16 + m15;
                wr[s] = aread(W3, 0, m, k);
                wi[s] = aread(W3, 1, m, k);
            }
            f16x8 br[2], bi[2];
            #pragma unroll
            for (int t = 0; t < 2; ++t) {
                br[t] = read_frag(Up + 0 * PLSZ, t * 16 + m15, k);
                bi[t] = read_frag(Up + 1 * PLSZ, t * 16 + m15, k);
            }
            #pragma unroll
            for (int s = 0; s < 2; ++s)
                #pragma unroll
                for (int t = 0; t < 2; ++t) {
                    accR[s][t] = mfma16h(wr[s], br[t], accR[s][t]);
                    accM[s][t] = mfma16h(wi[s], bi[t], accM[s][t]);
                    accI[s][t] = mfma16h(wr[s], bi[t], accI[s][t]);
                    accI[s][t] = mfma16h(wi[s], br[t], accI[s][t]);
                }
        }
    }

    #pragma unroll
    for (int s = 0; s < 2; ++s) {
        #pragma unroll
        for (int t = 0; t < 2; ++t) {
            int n = t * 16 + m15;
            if (n < ncols) {
                #pragma unroll
                for (int reg = 0; reg < 4; ++reg) {
                    int m = w * 32 + s * 16 + quad * 4 + reg;
                    Uhat[(size_t)(b * 128 + m) * LF + l0 + n] =
                        make_float2(accR[s][t][reg] - accM[s][t][reg], accI[s][t][reg]);
                }
            }
        }
    }
}

// ---------------------------------------------------------------------------
extern "C" void kernel_launch(void* const* d_in, const int* in_sizes, int n_in,
                              void* d_out, int out_size, void* d_ws, size_t ws_size,
                              hipStream_t stream) {
    const float* u    = (const float*)d_in[0];   // (B,H,L)
    const float* C_ri = (const float*)d_in[1];   // (H,P,2)
    const float* D_ri = (const float*)d_in[2];   // (H,H,2)
    const float* B_ri = (const float*)d_in[3];   // (P,H,2)
    const float* Lam  = (const float*)d_in[4];   // (P,2)
    float* out = (float*)d_out;

    float2* Uhat = (float2*)d_ws;                          // 1024*2049 float2 = 16 MiB
    _Float16* W1 = (_Float16*)(Uhat + (size_t)NROWS * LF);
    _Float16* W2 = W1 + 2 * WPLSZ;
    _Float16* W3 = W2 + 2 * WPLSZ;
    float2* tw = (float2*)(W3 + 2 * WPLSZ);                // 2048 float2 = 16 KB

    prep_all_k<<<152, 256, 0, stream>>>(B_ri, C_ri, D_ri, W1, W2, W3, tw);
    rfft_rows_k<<<NROWS, 256, 0, stream>>>(u, Uhat, tw);
    mixmm_k<<<Bn * NTILES, 256, 0, stream>>>(Uhat, W1, W2, W3, Lam);
    irfft_gelu_k<<<NROWS, 256, 0, stream>>>(Uhat, out, tw);
}

// Round 10
// 153.796 us; speedup vs baseline: 1.0447x; 1.0447x over previous
//
#include <hip/hip_runtime.h>
#include <math.h>

#define Bn 8
#define Hn 128
#define Pn 128
#define Ln 4096
#define LF 2049           // Ln/2 + 1
#define NROWS (Bn*Hn)     // 1024
#define NT 32             // frequency columns per mixmm block
#define NTILES 65         // ceil(2049/32) per batch
#define PLSZ 4096         // halfs per data plane (32 x 128)
#define WPLSZ 16384       // halfs per weight plane (128 x 128)
#define TSCALE 64.0f      // T stored as T/64 (fp16 range guard); W2 pre-scaled x64

// LDS skew for FFT buffers: +1 float2 every 16 -> strided Stockham writes <=2-way
#define SKEW(a) ((a) + ((a) >> 4))
#define FBUF 2176          // SKEW(2047)+1 rounded up

typedef _Float16 f16x8 __attribute__((ext_vector_type(8)));
typedef float f32x4 __attribute__((ext_vector_type(4)));

__device__ __forceinline__ void fsincos(float a, float* s, float* c) {
    *s = __sinf(a);
    *c = __cosf(a);
}

// ---------------------------------------------------------------------------
// prep (ONE kernel, latency-fixed): r9's version ran 46.8 us at 2% occupancy
// — every loop iteration was a dependent global-load -> sincos -> FMA chain
// (~430 cyc exposed). Now: 128-entry unit-root LDS table (no in-loop
// transcendentals) + inputs staged/streamed through LDS (one waitcnt per 16
// iterations instead of per iteration).
//   blocks   0- 63: W1[p][h] = (B_bar @ F)[p][h]
//   blocks  64-127: W2[h][p] = (Finv @ C)[h][p] * TSCALE
//   blocks 128-143: W3[h][q] = (Finv @ (D @ F))[h][q]  (two-phase via LDS)
//   blocks 144-151: tw table (256 entries each, accurate sincos)
// roots[m] = e^{+i pi m / 64}; forward DFT factor e^{-i th} = conj(roots).
// ---------------------------------------------------------------------------
__device__ __forceinline__ void write2(_Float16* __restrict__ W, int idx,
                                       float vr, float vi) {
    W[0 * WPLSZ + idx] = (_Float16)vr;
    W[1 * WPLSZ + idx] = (_Float16)vi;
}

__global__ __launch_bounds__(256) void prep_all_k(
        const float* __restrict__ B_ri, const float* __restrict__ C_ri,
        const float* __restrict__ D_ri,
        _Float16* __restrict__ W1, _Float16* __restrict__ W2,
        _Float16* __restrict__ W3, float2* __restrict__ tw) {
    __shared__ float2 roots[128];      // 1 KB
    __shared__ float2 stage[2048];     // 16 KB input chunk
    __shared__ float2 Gs[8 * 128];     // 8 KB (W3 phase-1 result)
    const int bid = blockIdx.x;
    const int tid = threadIdx.x;

    if (tid < 128) {
        float ang = 3.14159265358979f * (float)tid / 64.0f;
        float sw, cw; fsincos(ang, &sw, &cw);
        roots[tid] = make_float2(cw, sw);
    }
    __syncthreads();

    if (bid < 64) {
        // W1[p][h] = sum_q B[p][q] e^{-i pi (q h)/64}; rows p=2bid,2bid+1 in LDS
        const float2* B2f = (const float2*)B_ri;
        stage[tid] = B2f[bid * 256 + tid];
        __syncthreads();
        const int pl = tid >> 7, h = tid & 127;
        float sr = 0.f, si = 0.f;
        #pragma unroll 8
        for (int q = 0; q < 128; ++q) {
            float2 rt = roots[(q * h) & 127];
            float2 bv = stage[(pl << 7) + q];
            sr += bv.x * rt.x + bv.y * rt.y;
            si += bv.y * rt.x - bv.x * rt.y;
        }
        write2(W1, bid * 256 + tid, sr, si);
    } else if (bid < 128) {
        // W2[h][p] = (1/128) sum_h2 C[h2][p] e^{+i pi (h h2)/64}; C streamed
        const int bid2 = bid - 64;
        const float2* C2f = (const float2*)C_ri;
        const int h = 2 * bid2 + (tid >> 7), p = tid & 127;
        float sr = 0.f, si = 0.f;
        for (int chunk = 0; chunk < 8; ++chunk) {
            __syncthreads();
            #pragma unroll
            for (int i = 0; i < 8; ++i) stage[tid + i * 256] = C2f[chunk * 2048 + tid + i * 256];
            __syncthreads();
            #pragma unroll
            for (int j = 0; j < 16; ++j) {
                int h2 = chunk * 16 + j;
                float2 cv = stage[j * 128 + p];
                float2 rt = roots[(h * h2) & 127];
                sr += cv.x * rt.x - cv.y * rt.y;
                si += cv.x * rt.y + cv.y * rt.x;
            }
        }
        write2(W2, bid2 * 256 + tid, sr * (TSCALE / 128.0f), si * (TSCALE / 128.0f));
    } else if (bid < 144) {
        // W3 = (Finv @ D) @ F, two-phase. h = h0+hh (8 rows/block).
        const int h0 = (bid - 128) * 8;
        const int hh = tid >> 5, ci = tid & 31;
        const float2* D2f = (const float2*)D_ri;
        float2 g[4];
        #pragma unroll
        for (int cc = 0; cc < 4; ++cc) g[cc] = make_float2(0.f, 0.f);
        for (int chunk = 0; chunk < 8; ++chunk) {
            __syncthreads();
            #pragma unroll
            for (int i = 0; i < 8; ++i) stage[tid + i * 256] = D2f[chunk * 2048 + tid + i * 256];
            __syncthreads();
            #pragma unroll
            for (int j = 0; j < 16; ++j) {
                int a = chunk * 16 + j;
                float2 rt = roots[((h0 + hh) * a) & 127];
                #pragma unroll
                for (int cc = 0; cc < 4; ++cc) {
                    float2 dv = stage[j * 128 + ci + 32 * cc];
                    g[cc].x += dv.x * rt.x - dv.y * rt.y;
                    g[cc].y += dv.x * rt.y + dv.y * rt.x;
                }
            }
        }
        #pragma unroll
        for (int cc = 0; cc < 4; ++cc)
            Gs[hh * 128 + ci + 32 * cc] = make_float2(g[cc].x * (1.0f / 128.0f),
                                                      g[cc].y * (1.0f / 128.0f));
        __syncthreads();
        float2 wacc[4];
        #pragma unroll
        for (int qq = 0; qq < 4; ++qq) wacc[qq] = make_float2(0.f, 0.f);
        #pragma unroll 4
        for (int c = 0; c < 128; ++c) {
            float2 gv = Gs[hh * 128 + c];
            #pragma unroll
            for (int qq = 0; qq < 4; ++qq) {
                int q = ci + 32 * qq;
                float2 rt = roots[(c * q) & 127];
                wacc[qq].x += gv.x * rt.x + gv.y * rt.y;
                wacc[qq].y += gv.y * rt.x - gv.x * rt.y;
            }
        }
        #pragma unroll
        for (int qq = 0; qq < 4; ++qq)
            write2(W3, (h0 + hh) * 128 + ci + 32 * qq, wacc[qq].x, wacc[qq].y);
    } else {
        // FFT twiddle table, accurate sincos
        int m = (bid - 144) * 256 + tid;    // 0..2047
        float ang = -3.14159265358979f * (float)m / 1024.0f;
        float sw, cw;
        __sincosf(ang, &sw, &cw);
        tw[m] = make_float2(cw, sw);
    }
}

// ---------------------------------------------------------------------------
// 2048-pt Stockham FFT in LDS: radix-8 x3 + radix-4 (final) — byte-identical
// to r9 (twiddle table from global; clean A/B vs r8 via this round's total).
// ---------------------------------------------------------------------------
__device__ __forceinline__ float2 cadd2(float2 a, float2 b) { return make_float2(a.x + b.x, a.y + b.y); }
__device__ __forceinline__ float2 csub2(float2 a, float2 b) { return make_float2(a.x - b.x, a.y - b.y); }

template <int SIGN>
__device__ __forceinline__ void dft4(float2 a0, float2 a1, float2 a2, float2 a3,
                                     float2& y0, float2& y1, float2& y2, float2& y3) {
    float t0x = a0.x + a2.x, t0y = a0.y + a2.y;
    float t1x = a0.x - a2.x, t1y = a0.y - a2.y;
    float t2x = a1.x + a3.x, t2y = a1.y + a3.y;
    float t3x = a1.x - a3.x, t3y = a1.y - a3.y;
    y0 = make_float2(t0x + t2x, t0y + t2y);
    y2 = make_float2(t0x - t2x, t0y - t2y);
    y1 = make_float2(t1x - (float)SIGN * t3y, t1y + (float)SIGN * t3x);
    y3 = make_float2(t1x + (float)SIGN * t3y, t1y - (float)SIGN * t3x);
}

template <int SIGN>
__device__ __forceinline__ void fft2048(float2* bufA, float2* bufB,
                                        const float2* __restrict__ tw) {
    const int tid = threadIdx.x;
    float2* src = bufA;
    float2* dst = bufB;
    #pragma unroll
    for (int stg = 0; stg < 3; ++stg) {
        const int ls = 3 * stg;           // s = 8^stg
        const int k = tid;                // 256 butterflies
        const int q = k & ((1 << ls) - 1);
        const int mbase = k - q;          // p << ls  ==  p*2048/n
        float2 a[8];
        #pragma unroll
        for (int u = 0; u < 8; ++u) a[u] = src[SKEW(k + (u << 8))];
        float2 t1 = tw[mbase],     t2 = tw[2 * mbase], t3 = tw[3 * mbase];
        float2 t4 = tw[4 * mbase], t5 = tw[5 * mbase], t6 = tw[6 * mbase];
        float2 t7 = tw[7 * mbase];
        float2 A0, A1, A2, A3, B0, B1, B2, B3;
        dft4<SIGN>(a[0], a[2], a[4], a[6], A0, A1, A2, A3);
        dft4<SIGN>(a[1], a[3], a[5], a[7], B0, B1, B2, B3);
        const float c45 = 0.70710678118655f;
        float2 w1 = make_float2(c45 * (B1.x - (float)SIGN * B1.y), c45 * ((float)SIGN * B1.x + B1.y));
        float2 w2 = make_float2(-(float)SIGN * B2.y, (float)SIGN * B2.x);
        float2 w3 = make_float2(c45 * (-B3.x - (float)SIGN * B3.y), c45 * ((float)SIGN * B3.x - B3.y));
        float2 b[8];
        b[0] = cadd2(A0, B0);  b[4] = csub2(A0, B0);
        b[1] = cadd2(A1, w1);  b[5] = csub2(A1, w1);
        b[2] = cadd2(A2, w2);  b[6] = csub2(A2, w2);
        b[3] = cadd2(A3, w3);  b[7] = csub2(A3, w3);
        float2 twj[8];
        twj[1] = t1; twj[2] = t2; twj[3] = t3; twj[4] = t4;
        twj[5] = t5; twj[6] = t6; twj[7] = t7;
        #pragma unroll
        for (int j = 1; j < 8; ++j) {
            float cj = twj[j].x;
            float sj = (float)SIGN * twj[j].y;
            b[j] = make_float2(b[j].x * cj + b[j].y * sj, -b[j].x * sj + b[j].y * cj);
        }
        const int base = q + (mbase << 3);
        #pragma unroll
        for (int j = 0; j < 8; ++j) dst[SKEW(base + (j << ls))] = b[j];
        __syncthreads();
        float2* t = src; src = dst; dst = t;
    }
    #pragma unroll
    for (int r = 0; r < 2; ++r) {
        int k = tid + (r << 8);
        float2 a0 = src[SKEW(k)];
        float2 a1 = src[SKEW(k + 512)];
        float2 a2 = src[SKEW(k + 1024)];
        float2 a3 = src[SKEW(k + 1536)];
        float2 y0, y1, y2, y3;
        dft4<SIGN>(a0, a1, a2, a3, y0, y1, y2, y3);
        dst[SKEW(k)] = y0;
        dst[SKEW(k + 512)] = y1;
        dst[SKEW(k + 1024)] = y2;
        dst[SKEW(k + 1536)] = y3;
    }
    __syncthreads();
}

__global__ __launch_bounds__(256, 4) void rfft_rows_k(const float* __restrict__ u,
                                                      float2* __restrict__ Uhat,
                                                      const float2* __restrict__ tw) {
    __shared__ __align__(16) float2 bufA[FBUF];
    __shared__ __align__(16) float2 bufB[FBUF];
    const int row = blockIdx.x;
    const int tid = threadIdx.x;
    const float4* up4 = (const float4*)(u + (size_t)row * Ln);
    #pragma unroll
    for (int r = 0; r < 4; ++r) {
        float4 v = up4[tid + (r << 8)];
        int i = 2 * (tid + (r << 8));
        bufA[SKEW(i)] = make_float2(v.x, v.y);
        bufA[SKEW(i + 1)] = make_float2(v.z, v.w);
    }
    __syncthreads();
    fft2048<-1>(bufA, bufB, tw);
    float2* op = Uhat + (size_t)row * LF;
    for (int l = tid; l < 1025; l += 256) {
        float2 Zl = bufA[SKEW(l)];
        float2 Zm = bufA[SKEW((2048 - l) & 2047)];
        float2 Fe = make_float2(0.5f * (Zl.x + Zm.x), 0.5f * (Zl.y - Zm.y));
        float2 Dv = make_float2(0.5f * (Zl.x - Zm.x), 0.5f * (Zl.y + Zm.y));
        float2 Fo = make_float2(Dv.y, -Dv.x);                 // Dv / i
        float s, c; fsincos(-3.14159265358979f * (float)l / 2048.0f, &s, &c);
        float2 TF = make_float2(Fo.x * c - Fo.y * s, Fo.x * s + Fo.y * c);
        op[l] = make_float2(Fe.x + TF.x, Fe.y + TF.y);
        op[2048 - l] = make_float2(Fe.x - TF.x, -(Fe.y - TF.y));   // conj(Fe - TF)
    }
}

__global__ __launch_bounds__(256, 4) void irfft_gelu_k(const float2* __restrict__ Uhat,
                                                       float* __restrict__ out,
                                                       const float2* __restrict__ tw) {
    __shared__ __align__(16) float2 bufA[FBUF];
    __shared__ __align__(16) float2 bufB[FBUF];
    const int row = blockIdx.x;
    const int tid = threadIdx.x;
    const float2* wp = Uhat + (size_t)row * LF;
    for (int l = tid; l < 1025; l += 256) {
        float2 Ul = wp[l];
        float2 Um = wp[2048 - l];
        float2 Fe = make_float2(0.5f * (Ul.x + Um.x), 0.5f * (Ul.y - Um.y));
        float2 Dv = make_float2(0.5f * (Ul.x - Um.x), 0.5f * (Ul.y + Um.y));
        float s, c; fsincos(3.14159265358979f * (float)l / 2048.0f, &s, &c);
        float2 Fo = make_float2(Dv.x * c - Dv.y * s, Dv.x * s + Dv.y * c);
        bufA[SKEW(l)] = make_float2(Fe.x - Fo.y, Fe.y + Fo.x);          // Fe + i Fo
        if (l >= 1 && l <= 1023)
            bufA[SKEW(2048 - l)] = make_float2(Fe.x + Fo.y, Fo.x - Fe.y); // conj(Fe)+i conj(Fo)
    }
    __syncthreads();
    fft2048<1>(bufA, bufB, tw);
    float4* op4 = (float4*)(out + (size_t)row * Ln);
    #pragma unroll
    for (int r = 0; r < 4; ++r) {
        int n = 2 * (tid + (r << 8));
        float2 z0 = bufA[SKEW(n)];
        float2 z1 = bufA[SKEW(n + 1)];
        float y0 = z0.x * (1.0f / 2048.0f);
        float y1 = z0.y * (1.0f / 2048.0f);
        float y2 = z1.x * (1.0f / 2048.0f);
        float y3 = z1.y * (1.0f / 2048.0f);
        op4[tid + (r << 8)] = make_float4(
            0.5f * y0 * (1.0f + erff(y0 * 0.70710678118655f)),
            0.5f * y1 * (1.0f + erff(y1 * 0.70710678118655f)),
            0.5f * y2 * (1.0f + erff(y2 * 0.70710678118655f)),
            0.5f * y3 * (1.0f + erff(y3 * 0.70710678118655f)));
    }
}

// ---------------------------------------------------------------------------
// mixmm: byte-identical to r7/r8/r9.
// ---------------------------------------------------------------------------
__device__ __forceinline__ f32x4 mfma16h(f16x8 a, f16x8 b, f32x4 c) {
    return __builtin_amdgcn_mfma_f32_16x16x32_f16(a, b, c, 0, 0, 0);
}
__device__ __forceinline__ f16x8 read_frag(const _Float16* plane, int n, int k) {
    int ksw = k ^ ((n & 7) << 3);
    return *(const f16x8*)(plane + n * 128 + ksw);
}
__device__ __forceinline__ f16x8 aread(const _Float16* W, int pl, int m, int k) {
    return *(const f16x8*)(W + pl * WPLSZ + m * 128 + k);
}

__global__ __launch_bounds__(256, 4) void mixmm_k(float2* __restrict__ Uhat,
                                                  const _Float16* __restrict__ W1,
                                                  const _Float16* __restrict__ W2,
                                                  const _Float16* __restrict__ W3,
                                                  const float* __restrict__ Lam) {
    __shared__ __align__(16) _Float16 Up[2 * PLSZ];      // 16 KB  {r, i}
    __shared__ __align__(16) _Float16 Tp[2 * PLSZ];      // 16 KB  {r, i}

    const int tid = threadIdx.x;
    const int b = blockIdx.x / NTILES;
    const int tile = blockIdx.x % NTILES;
    const int l0 = tile * NT;
    const int ncols = (LF - l0) < NT ? (LF - l0) : NT;

    {
        int n = tid & 31, kc = tid >> 5;
        float2 v[16];
        #pragma unroll
        for (int j = 0; j < 16; ++j) {
            int h = kc * 16 + j;
            v[j] = (n < ncols) ? Uhat[(size_t)(b * 128 + h) * LF + l0 + n]
                               : make_float2(0.f, 0.f);
        }
        #pragma unroll
        for (int jc = 0; jc < 2; ++jc) {
            f16x8 fr, fi;
            #pragma unroll
            for (int j = 0; j < 8; ++j) {
                fr[j] = (_Float16)v[jc * 8 + j].x;
                fi[j] = (_Float16)v[jc * 8 + j].y;
            }
            int ksw = (kc * 16 + jc * 8) ^ ((n & 7) << 3);
            *(f16x8*)(Up + 0 * PLSZ + n * 128 + ksw) = fr;
            *(f16x8*)(Up + 1 * PLSZ + n * 128 + ksw) = fi;
        }
    }
    __syncthreads();

    const int lane = tid & 63;
    const int w = tid >> 6;
    const int m15 = lane & 15;
    const int quad = lane >> 4;

    f32x4 accR[2][2], accM[2][2], accI[2][2];
    #pragma unroll
    for (int s = 0; s < 2; ++s)
        #pragma unroll
        for (int t = 0; t < 2; ++t) {
            accR[s][t] = (f32x4)0.f; accM[s][t] = (f32x4)0.f; accI[s][t] = (f32x4)0.f;
        }

    #pragma unroll
    for (int kb = 0; kb < 4; ++kb) {
        int k = kb * 32 + quad * 8;
        f16x8 wr[2], wi[2];
        #pragma unroll
        for (int s = 0; s < 2; ++s) {
            int m = w * 32 + s * 16 + m15;
            wr[s] = aread(W1, 0, m, k);
            wi[s] = aread(W1, 1, m, k);
        }
        f16x8 br[2], bi[2];
        #pragma unroll
        for (int t = 0; t < 2; ++t) {
            br[t] = read_frag(Up + 0 * PLSZ, t * 16 + m15, k);
            bi[t] = read_frag(Up + 1 * PLSZ, t * 16 + m15, k);
        }
        #pragma unroll
        for (int s = 0; s < 2; ++s)
            #pragma unroll
            for (int t = 0; t < 2; ++t) {
                accR[s][t] = mfma16h(wr[s], br[t], accR[s][t]);
                accM[s][t] = mfma16h(wi[s], bi[t], accM[s][t]);
                accI[s][t] = mfma16h(wr[s], bi[t], accI[s][t]);
                accI[s][t] = mfma16h(wi[s], br[t], accI[s][t]);
            }
    }

    #pragma unroll
    for (int s = 0; s < 2; ++s) {
        #pragma unroll
        for (int reg = 0; reg < 4; ++reg) {
            int p = w * 32 + s * 16 + quad * 4 + reg;
            float2 lamv = ((const float2*)Lam)[p];
            float dr = -lamv.x;
            #pragma unroll
            for (int t = 0; t < 2; ++t) {
                int n = t * 16 + m15;
                int l = l0 + n;
                float di = 3.14159265358979f * (float)l / 2048.0f - lamv.y;
                float inv = (1.0f / TSCALE) / (dr * dr + di * di);
                float xr = accR[s][t][reg] - accM[s][t][reg];
                float xi = accI[s][t][reg];
                float tr = (xr * dr + xi * di) * inv;
                float ti = (xi * dr - xr * di) * inv;
                int off = n * 128 + (p ^ ((n & 7) << 3));
                Tp[0 * PLSZ + off] = (_Float16)tr;
                Tp[1 * PLSZ + off] = (_Float16)ti;
            }
        }
    }
    __syncthreads();

    #pragma unroll
    for (int s = 0; s < 2; ++s)
        #pragma unroll
        for (int t = 0; t < 2; ++t) {
            accR[s][t] = (f32x4)0.f; accM[s][t] = (f32x4)0.f; accI[s][t] = (f32x4)0.f;
        }

    #pragma unroll
    for (int kb = 0; kb < 4; ++kb) {
        int k = kb * 32 + quad * 8;
        {
            f16x8 wr[2], wi[2];
            #pragma unroll
            for (int s = 0; s < 2; ++s) {
                int m = w * 32 + s * 16 + m15;
                wr[s] = aread(W2, 0, m, k);
                wi[s] = aread(W2, 1, m, k);
            }
            f16x8 br[2], bi[2];
            #pragma unroll
            for (int t = 0; t < 2; ++t) {
                br[t] = read_frag(Tp + 0 * PLSZ, t * 16 + m15, k);
                bi[t] = read_frag(Tp + 1 * PLSZ, t * 16 + m15, k);
            }
            #pragma unroll
            for (int s = 0; s < 2; ++s)
                #pragma unroll
                for (int t = 0; t < 2; ++t) {
                    accR[s][t] = mfma16h(wr[s], br[t], accR[s][t]);
                    accM[s][t] = mfma16h(wi[s], bi[t], accM[s][t]);
                    accI[s][t] = mfma16h(wr[s], bi[t], accI[s][t]);
                    accI[s][t] = mfma16h(wi[s], br[t], accI[s][t]);
                }
        }
        {
            f16x8 wr[2], wi[2];
            #pragma unroll
            for (int s = 0; s < 2; ++s) {
                int m = w * 32 + s * 16 + m15;
                wr[s] = aread(W3, 0, m, k);
                wi[s] = aread(W3, 1, m, k);
            }
            f16x8 br[2], bi[2];
            #pragma unroll
            for (int t = 0; t < 2; ++t) {
                br[t] = read_frag(Up + 0 * PLSZ, t * 16 + m15, k);
                bi[t] = read_frag(Up + 1 * PLSZ, t * 16 + m15, k);
            }
            #pragma unroll
            for (int s = 0; s < 2; ++s)
                #pragma unroll
                for (int t = 0; t < 2; ++t) {
                    accR[s][t] = mfma16h(wr[s], br[t], accR[s][t]);
                    accM[s][t] = mfma16h(wi[s], bi[t], accM[s][t]);
                    accI[s][t] = mfma16h(wr[s], bi[t], accI[s][t]);
                    accI[s][t] = mfma16h(wi[s], br[t], accI[s][t]);
                }
        }
    }

    #pragma unroll
    for (int s = 0; s < 2; ++s) {
        #pragma unroll
        for (int t = 0; t < 2; ++t) {
            int n = t * 16 + m15;
            if (n < ncols) {
                #pragma unroll
                for (int reg = 0; reg < 4; ++reg) {
                    int m = w * 32 + s * 16 + quad * 4 + reg;
                    Uhat[(size_t)(b * 128 + m) * LF + l0 + n] =
                        make_float2(accR[s][t][reg] - accM[s][t][reg], accI[s][t][reg]);
                }
            }
        }
    }
}

// ---------------------------------------------------------------------------
extern "C" void kernel_launch(void* const* d_in, const int* in_sizes, int n_in,
                              void* d_out, int out_size, void* d_ws, size_t ws_size,
                              hipStream_t stream) {
    const float* u    = (const float*)d_in[0];   // (B,H,L)
    const float* C_ri = (const float*)d_in[1];   // (H,P,2)
    const float* D_ri = (const float*)d_in[2];   // (H,H,2)
    const float* B_ri = (const float*)d_in[3];   // (P,H,2)
    const float* Lam  = (const float*)d_in[4];   // (P,2)
    float* out = (float*)d_out;

    float2* Uhat = (float2*)d_ws;                          // 1024*2049 float2 = 16 MiB
    _Float16* W1 = (_Float16*)(Uhat + (size_t)NROWS * LF);
    _Float16* W2 = W1 + 2 * WPLSZ;
    _Float16* W3 = W2 + 2 * WPLSZ;
    float2* tw = (float2*)(W3 + 2 * WPLSZ);                // 2048 float2 = 16 KB

    prep_all_k<<<152, 256, 0, stream>>>(B_ri, C_ri, D_ri, W1, W2, W3, tw);
    rfft_rows_k<<<NROWS, 256, 0, stream>>>(u, Uhat, tw);
    mixmm_k<<<Bn * NTILES, 256, 0, stream>>>(Uhat, W1, W2, W3, Lam);
    irfft_gelu_k<<<NROWS, 256, 0, stream>>>(Uhat, out, tw);
}